// Round 2
// baseline (15383.386 us; speedup 1.0000x reference)
//
// pendulumRNNSA — persistent-grid 2-layer LSTM (B=256,T=512,H=256) + deferred attention.
//
// Round 1: persistent RNN. 256 blocks (16 batch-groups x 16 hidden-groups), all
// co-resident. Each block keeps its 64-gate-row weight slices as MFMA B-frags in
// VGPRs (96 VGPR bf16), c-state in registers, and exchanges h through L2 with a
// device-scope two-level barrier (one per phase; layers software-pipelined so
// gates1(t) and gates2(t-1) share one phase). h exchanged as bf16 hi+lo pairs
// (~fp23) to keep recurrence numerics at round-0 level.
#include <hip/hip_runtime.h>
#include <hip/hip_bf16.h>

#define HD   256
#define TT   512
#define G4H  1024

typedef unsigned short u16;
typedef unsigned int   u32;
typedef __attribute__((ext_vector_type(8))) short  short8;
typedef __attribute__((ext_vector_type(4))) float  f32x4;

__device__ __forceinline__ float bf2f(u16 v) { return __uint_as_float(((u32)v) << 16); }
__device__ __forceinline__ u16 f2bf(float f) {
    u32 u = __float_as_uint(f);
    u32 r = u + 0x7fffu + ((u >> 16) & 1u);   // RNE
    return (u16)(r >> 16);
}
__device__ __forceinline__ float sigf(float x)  { return __builtin_amdgcn_rcpf(1.f + __expf(-x)); }
__device__ __forceinline__ float tanhf_(float x){ float e = __expf(-2.f * x);
                                                  return 2.f * __builtin_amdgcn_rcpf(1.f + e) - 1.f; }

__global__ void cvt_bf_kernel(const float* __restrict__ src, u16* __restrict__ dst, int n) {
    int idx = blockIdx.x * 256 + threadIdx.x;
    if (idx < n) dst[idx] = f2bf(src[idx]);
}

__global__ void bias_kernel(const float* __restrict__ a1, const float* __restrict__ b1,
                            const float* __restrict__ a2, const float* __restrict__ b2,
                            float* __restrict__ o1, float* __restrict__ o2) {
    int i = blockIdx.x * 256 + threadIdx.x;
    o1[i] = a1[i] + b1[i];
    o2[i] = a2[i] + b2[i];
}

// B-fragment loader: wave handles gate g=waveid, lane n = hidden-local, kq = k-quarter.
// frag[kk] holds W[row][kk*32 + kq*8 + j] (j=0..7) as bf16.
__device__ __forceinline__ void load_bfrag(const float* __restrict__ W, int row, int kq, short8* bw) {
#pragma unroll
    for (int kk = 0; kk < 8; ++kk) {
        const float* p = W + row * 256 + kk * 32 + kq * 8;
        short8 s;
#pragma unroll
        for (int j = 0; j < 8; ++j) s[j] = (short)f2bf(p[j]);
        bw[kk] = s;
    }
}

// two-level device barrier: 16 groups of 16 blocks, monotonic counters.
__device__ __forceinline__ void gbarrier(u32* bar, int blk, u32 p) {
    __syncthreads();                 // waits vmcnt(0): all block stores complete in L2
    if (threadIdx.x == 0) {
        u32* cnt  = bar + (blk >> 4) * 32;   // 128B apart
        u32* gcnt = bar + 16 * 32;
        u32 old = __hip_atomic_fetch_add(cnt, 1u, __ATOMIC_ACQ_REL, __HIP_MEMORY_SCOPE_AGENT);
        if (old == 16u * p - 1u)             // last of group this phase
            __hip_atomic_fetch_add(gcnt, 1u, __ATOMIC_ACQ_REL, __HIP_MEMORY_SCOPE_AGENT);
        while (__hip_atomic_load(gcnt, __ATOMIC_ACQUIRE, __HIP_MEMORY_SCOPE_AGENT) < 16u * p)
            __builtin_amdgcn_s_sleep(1);
    }
    __syncthreads();
}

// Hb layout: [parity][plane(hi/lo)][256 batch][256 hidden] u16.
__global__ __launch_bounds__(256) void lstm_persist(
    const float* __restrict__ x,
    const float* __restrict__ Wih1,
    const float* __restrict__ bias1,
    const float* __restrict__ bias2,
    const float* __restrict__ Whh1,
    const float* __restrict__ Wih2,
    const float* __restrict__ Whh2,
    u16* __restrict__ Hb1, u16* __restrict__ Hb2,
    u16* __restrict__ H2out, u32* bar)
{
    __shared__ __align__(16) u16 sh1hi[16 * 264], sh1lo[16 * 264];
    __shared__ __align__(16) u16 sh2hi[16 * 264], sh2lo[16 * 264];
    __shared__ float xs[TT * 16];
    __shared__ float gbuf1[4 * 16 * 18], gbuf2[4 * 16 * 18];
    __shared__ float wihs[64], b1s[64], b2s[64];

    const int tid = threadIdx.x;
    const int blk = blockIdx.x, gb = blk >> 4, hg = blk & 15;
    const int l = tid & 63, wv = tid >> 6;       // wave wv = gate index
    const int nloc = l & 15, kq = l >> 4;
    const int wrow = wv * 256 + hg * 16 + nloc;  // this lane's gate row

    short8 bW1[8], bW2[8], bW3[8];
    load_bfrag(Whh1, wrow, kq, bW1);
    load_bfrag(Wih2, wrow, kq, bW2);
    load_bfrag(Whh2, wrow, kq, bW3);

    for (int idx = tid; idx < 16 * TT; idx += 256) {
        int b = idx >> 9, t = idx & 511;
        xs[t * 16 + b] = x[(gb * 16 + b) * TT + t];
    }
    if (tid < 64) {
        int rr = (tid >> 4) * 256 + hg * 16 + (tid & 15);
        wihs[tid] = Wih1[rr]; b1s[tid] = bias1[rr]; b2s[tid] = bias2[rr];
    }
    const int cb = tid >> 4, ci = tid & 15;
    const int bg = gb * 16 + cb, ig = hg * 16 + ci;
    // zero own state patches (both parities/planes) — ws is poisoned each launch
#pragma unroll
    for (int pp = 0; pp < 4; ++pp) {
        Hb1[(pp * 256 + bg) * 256 + ig] = 0;
        Hb2[(pp * 256 + bg) * 256 + ig] = 0;
    }
    float c1 = 0.f, c2 = 0.f;

    u32 p = 1;
    gbarrier(bar, blk, p); ++p;

    const int aoff = nloc * 264 + kq * 8;
    const int sb = tid >> 4, scol = (tid & 15) * 16;

    for (int k = 0; k <= TT; ++k, ++p) {
        const int rp = k & 1, wp = rp ^ 1;
        // stage h1(k-1), h2(k-2) (hi+lo planes) into LDS
        {
            const u16* s0 = Hb1 + ((rp * 2 + 0) * 256 + gb * 16 + sb) * 256 + scol;
            const u16* s1 = Hb1 + ((rp * 2 + 1) * 256 + gb * 16 + sb) * 256 + scol;
            const u16* s2 = Hb2 + ((rp * 2 + 0) * 256 + gb * 16 + sb) * 256 + scol;
            const u16* s3 = Hb2 + ((rp * 2 + 1) * 256 + gb * 16 + sb) * 256 + scol;
            *(uint4*)(sh1hi + sb * 264 + scol)     = *(const uint4*)s0;
            *(uint4*)(sh1hi + sb * 264 + scol + 8) = *(const uint4*)(s0 + 8);
            *(uint4*)(sh1lo + sb * 264 + scol)     = *(const uint4*)s1;
            *(uint4*)(sh1lo + sb * 264 + scol + 8) = *(const uint4*)(s1 + 8);
            *(uint4*)(sh2hi + sb * 264 + scol)     = *(const uint4*)s2;
            *(uint4*)(sh2hi + sb * 264 + scol + 8) = *(const uint4*)(s2 + 8);
            *(uint4*)(sh2lo + sb * 264 + scol)     = *(const uint4*)s3;
            *(uint4*)(sh2lo + sb * 264 + scol + 8) = *(const uint4*)(s3 + 8);
        }
        __syncthreads();

        f32x4 acc1a = {0,0,0,0}, acc1b = {0,0,0,0};
        f32x4 acc2a = {0,0,0,0}, acc2b = {0,0,0,0};
        if (k < TT) {
#pragma unroll
            for (int kk = 0; kk < 8; ++kk) {
                short8 a = *(const short8*)(sh1hi + aoff + kk * 32);
                acc1a = __builtin_amdgcn_mfma_f32_16x16x32_bf16(a, bW1[kk], acc1a, 0, 0, 0);
                a = *(const short8*)(sh1lo + aoff + kk * 32);
                acc1b = __builtin_amdgcn_mfma_f32_16x16x32_bf16(a, bW1[kk], acc1b, 0, 0, 0);
            }
        }
        if (k > 0) {
#pragma unroll
            for (int kk = 0; kk < 8; ++kk) {
                short8 a = *(const short8*)(sh1hi + aoff + kk * 32);
                acc2a = __builtin_amdgcn_mfma_f32_16x16x32_bf16(a, bW2[kk], acc2a, 0, 0, 0);
                a = *(const short8*)(sh1lo + aoff + kk * 32);
                acc2b = __builtin_amdgcn_mfma_f32_16x16x32_bf16(a, bW2[kk], acc2b, 0, 0, 0);
                a = *(const short8*)(sh2hi + aoff + kk * 32);
                acc2a = __builtin_amdgcn_mfma_f32_16x16x32_bf16(a, bW3[kk], acc2a, 0, 0, 0);
                a = *(const short8*)(sh2lo + aoff + kk * 32);
                acc2b = __builtin_amdgcn_mfma_f32_16x16x32_bf16(a, bW3[kk], acc2b, 0, 0, 0);
            }
        }
        // D layout: col(n)=lane&15, row(m)=(lane>>4)*4+reg  -> gbuf[g][batch m][i n]
#pragma unroll
        for (int r = 0; r < 4; ++r) {
            int m = (l >> 4) * 4 + r;
            gbuf1[(wv * 16 + m) * 18 + nloc] = acc1a[r] + acc1b[r];
            gbuf2[(wv * 16 + m) * 18 + nloc] = acc2a[r] + acc2b[r];
        }
        __syncthreads();

        if (k < TT) {   // cell 1, t = k
            float xv = xs[k * 16 + cb];
            float g0 = gbuf1[(0 * 16 + cb) * 18 + ci] + xv * wihs[ci]      + b1s[ci];
            float g1 = gbuf1[(1 * 16 + cb) * 18 + ci] + xv * wihs[16 + ci] + b1s[16 + ci];
            float g2 = gbuf1[(2 * 16 + cb) * 18 + ci] + xv * wihs[32 + ci] + b1s[32 + ci];
            float g3 = gbuf1[(3 * 16 + cb) * 18 + ci] + xv * wihs[48 + ci] + b1s[48 + ci];
            float ii = sigf(g0), ff = sigf(g1), gg = tanhf_(g2), oo = sigf(g3);
            c1 = ff * c1 + ii * gg;
            float h = oo * tanhf_(c1);
            u16 hi = f2bf(h); float lo = h - bf2f(hi);
            Hb1[((wp * 2 + 0) * 256 + bg) * 256 + ig] = hi;
            Hb1[((wp * 2 + 1) * 256 + bg) * 256 + ig] = f2bf(lo);
        }
        if (k > 0) {    // cell 2, t = k-1
            float g0 = gbuf2[(0 * 16 + cb) * 18 + ci] + b2s[ci];
            float g1 = gbuf2[(1 * 16 + cb) * 18 + ci] + b2s[16 + ci];
            float g2 = gbuf2[(2 * 16 + cb) * 18 + ci] + b2s[32 + ci];
            float g3 = gbuf2[(3 * 16 + cb) * 18 + ci] + b2s[48 + ci];
            float ii = sigf(g0), ff = sigf(g1), gg = tanhf_(g2), oo = sigf(g3);
            c2 = ff * c2 + ii * gg;
            float h = oo * tanhf_(c2);
            u16 hi = f2bf(h); float lo = h - bf2f(hi);
            Hb2[((wp * 2 + 0) * 256 + bg) * 256 + ig] = hi;
            Hb2[((wp * 2 + 1) * 256 + bg) * 256 + ig] = f2bf(lo);
            H2out[(bg * TT + (k - 1)) * 256 + ig] = hi;
        }
        gbarrier(bar, blk, p);
    }
}

// ---- attention pass A: Y = tanh(H2 @ Wa1^T + ba1)
__global__ __launch_bounds__(256) void attn_a_kernel(
    const u16*  __restrict__ Wa1b, const float* __restrict__ ba1,
    const u16*  __restrict__ H2, u16* __restrict__ Y)
{
    __shared__ u16 sW[256 * 258];
    __shared__ float sh[HD];
    const int tid = threadIdx.x;
    for (int i = tid; i < 256 * 256; i += 256) {
        int r = i >> 8, c = i & 255;
        sW[r * 258 + c] = Wa1b[i];
    }
    const float bj = ba1[tid];
    const int row0 = blockIdx.x * 64;
    for (int rr = 0; rr < 64; ++rr) {
        const int row = row0 + rr;
        __syncthreads();
        sh[tid] = bf2f(H2[row * HD + tid]);
        __syncthreads();
        float acc = bj;
        const u16* wrow = sW + tid * 258;
#pragma unroll 8
        for (int k = 0; k < 256; k += 2) {
            u32 w2 = *(const u32*)(wrow + k);
            float2 hp = *(const float2*)(sh + k);
            acc += hp.x * bf2f((u16)(w2 & 0xffffu)) + hp.y * bf2f((u16)(w2 >> 16));
        }
        Y[row * HD + tid] = f2bf(tanhf(acc));
    }
}

// ---- attention pass B: softmax(Y@Wa2^T+ba2) -> out = (attn*h2)@Wo + bo
__global__ __launch_bounds__(256) void attn_b_kernel(
    const u16*  __restrict__ Wa2b, const float* __restrict__ ba2,
    const float* __restrict__ Wo, const float* __restrict__ bo,
    const u16*  __restrict__ H2, const u16* __restrict__ Y,
    float* __restrict__ out)
{
    __shared__ u16 sW[256 * 258];
    __shared__ float sy[HD], sh[HD];
    __shared__ float red[8];
    const int tid = threadIdx.x;
    const int lane = tid & 63, wid = tid >> 6;
    for (int i = tid; i < 256 * 256; i += 256) {
        int r = i >> 8, c = i & 255;
        sW[r * 258 + c] = Wa2b[i];
    }
    const float bj  = ba2[tid];
    const float wo  = Wo[tid];
    const float bov = bo[0];
    const int row0 = blockIdx.x * 64;
    for (int rr = 0; rr < 64; ++rr) {
        const int row = row0 + rr;
        __syncthreads();
        sy[tid] = bf2f(Y[row * HD + tid]);
        sh[tid] = bf2f(H2[row * HD + tid]);
        __syncthreads();
        float acc = bj;
        const u16* wrow = sW + tid * 258;
#pragma unroll 8
        for (int k = 0; k < 256; k += 2) {
            u32 w2 = *(const u32*)(wrow + k);
            float2 yp = *(const float2*)(sy + k);
            acc += yp.x * bf2f((u16)(w2 & 0xffffu)) + yp.y * bf2f((u16)(w2 >> 16));
        }
        float m = acc;
        for (int off = 32; off >= 1; off >>= 1) m = fmaxf(m, __shfl_xor(m, off));
        if (lane == 0) red[wid] = m;
        __syncthreads();
        m = fmaxf(fmaxf(red[0], red[1]), fmaxf(red[2], red[3]));
        __syncthreads();
        float e = expf(acc - m);
        float s = e;
        for (int off = 32; off >= 1; off >>= 1) s += __shfl_xor(s, off);
        if (lane == 0) red[wid] = s;
        __syncthreads();
        s = red[0] + red[1] + red[2] + red[3];
        __syncthreads();
        float contrib = (e / s) * sh[tid] * wo;
        for (int off = 32; off >= 1; off >>= 1) contrib += __shfl_xor(contrib, off);
        if (lane == 0) red[wid] = contrib;
        __syncthreads();
        if (tid == 0) out[row] = red[0] + red[1] + red[2] + red[3] + bov;
    }
}

extern "C" void kernel_launch(void* const* d_in, const int* in_sizes, int n_in,
                              void* d_out, int out_size, void* d_ws, size_t ws_size,
                              hipStream_t stream) {
    const float* x    = (const float*)d_in[0];
    const float* Wih1 = (const float*)d_in[1];
    const float* bih1 = (const float*)d_in[2];
    const float* Whh1 = (const float*)d_in[3];
    const float* bhh1 = (const float*)d_in[4];
    const float* Wih2 = (const float*)d_in[5];
    const float* bih2 = (const float*)d_in[6];
    const float* Whh2 = (const float*)d_in[7];
    const float* bhh2 = (const float*)d_in[8];
    const float* Wa1  = (const float*)d_in[9];
    const float* ba1  = (const float*)d_in[10];
    const float* Wa2  = (const float*)d_in[11];
    const float* ba2  = (const float*)d_in[12];
    const float* Wo   = (const float*)d_in[13];
    const float* bo   = (const float*)d_in[14];

    char* ws = (char*)d_ws;
    u16*   Wa1b  = (u16*)(ws + 0);                  // 128 KB
    u16*   Wa2b  = (u16*)(ws + 131072);             // 128 KB
    float* bias1 = (float*)(ws + 262144);           // 4 KB
    float* bias2 = (float*)(ws + 266240);           // 4 KB
    u32*   bar   = (u32*)(ws + 270336);             // 4 KB
    u16*   Hb1   = (u16*)(ws + 524288);             // 512 KB [2][2][256][256]
    u16*   Hb2   = (u16*)(ws + 1048576);            // 512 KB
    u16*   H2    = (u16*)(ws + 2097152);            // 64 MB
    u16*   Y     = (u16*)(ws + 2097152 + 67108864); // 64 MB
    float* out   = (float*)d_out;

    hipMemsetAsync(bar, 0, 4096, stream);
    bias_kernel<<<4, 256, 0, stream>>>(bih1, bhh1, bih2, bhh2, bias1, bias2);
    cvt_bf_kernel<<<256, 256, 0, stream>>>(Wa1, Wa1b, 65536);
    cvt_bf_kernel<<<256, 256, 0, stream>>>(Wa2, Wa2b, 65536);

    lstm_persist<<<256, 256, 0, stream>>>(x, Wih1, bias1, bias2,
                                          Whh1, Wih2, Whh2, Hb1, Hb2, H2, bar);
    attn_a_kernel<<<2048, 256, 0, stream>>>(Wa1b, ba1, H2, Y);
    attn_b_kernel<<<2048, 256, 0, stream>>>(Wa2b, ba2, Wo, bo, H2, Y, out);
}

// Round 3
// 2707.291 us; speedup vs baseline: 5.6822x; 5.6822x over previous
//
// pendulumRNNSA — persistent 2-layer LSTM (B=256,T=512,H=256) + fused MFMA attention.
//
// Round 3:
//  * h-exchange via RELAXED agent-scope atomics (sc1: write-through / L2-bypass)
//    -> NO acquire/release fences (round 2's 23us/phase was buffer_wbl2+buffer_inv
//    per phase). Ordering: __syncthreads drains vmcnt(0) before leader RMW.
//  * Barrier per batch-group (16 blocks each, own counter line) instead of global
//    256-block barrier; relaxed poll + bounded-spin ACQUIRE fallback (no hang).
//  * h packed hi|lo bf16 in one u32 (~fp23 recurrence precision, as round 1/2).
//  * Attention: ONE fused kernel, 64-row tiles, both matmuls via mfma_16x16x32_bf16
//    (B-frags streamed from L2), block-local softmax + weighted-sum epilogue.
#include <hip/hip_runtime.h>
#include <hip/hip_bf16.h>

#define HD   256
#define TT   512

typedef unsigned short u16;
typedef unsigned int   u32;
typedef unsigned long long u64;
typedef __attribute__((ext_vector_type(8))) short  short8;
typedef __attribute__((ext_vector_type(4))) float  f32x4;

__device__ __forceinline__ float bf2f(u16 v) { return __uint_as_float(((u32)v) << 16); }
__device__ __forceinline__ u16 f2bf(float f) {
    u32 u = __float_as_uint(f);
    u32 r = u + 0x7fffu + ((u >> 16) & 1u);   // RNE
    return (u16)(r >> 16);
}
__device__ __forceinline__ float sigf(float x)  { return __builtin_amdgcn_rcpf(1.f + __expf(-x)); }
__device__ __forceinline__ float tanhf_(float x){ float e = __expf(-2.f * x);
                                                  return 2.f * __builtin_amdgcn_rcpf(1.f + e) - 1.f; }

__global__ void cvt_bf_kernel(const float* __restrict__ src, u16* __restrict__ dst, int n) {
    int idx = blockIdx.x * 256 + threadIdx.x;
    if (idx < n) dst[idx] = f2bf(src[idx]);
}

__global__ void bias_kernel(const float* __restrict__ a1, const float* __restrict__ b1,
                            const float* __restrict__ a2, const float* __restrict__ b2,
                            float* __restrict__ o1, float* __restrict__ o2) {
    int i = blockIdx.x * 256 + threadIdx.x;
    o1[i] = a1[i] + b1[i];
    o2[i] = a2[i] + b2[i];
}

__device__ __forceinline__ void load_bfrag(const float* __restrict__ W, int row, int kq, short8* bw) {
#pragma unroll
    for (int kk = 0; kk < 8; ++kk) {
        const float* p = W + row * 256 + kk * 32 + kq * 8;
        short8 s;
#pragma unroll
        for (int j = 0; j < 8; ++j) s[j] = (short)f2bf(p[j]);
        bw[kk] = s;
    }
}

// per-batch-group barrier: 16 blocks, relaxed RMW + relaxed poll, acquire fallback.
__device__ __forceinline__ void gbarrier(u32* cnt, u32 target) {
    __syncthreads();     // drains vmcnt(0): this block's sc1 stores are at the coherent point
    if (threadIdx.x == 0) {
        __hip_atomic_fetch_add(cnt, 1u, __ATOMIC_RELAXED, __HIP_MEMORY_SCOPE_AGENT);
        int spins = 0;
        while (__hip_atomic_load(cnt, __ATOMIC_RELAXED, __HIP_MEMORY_SCOPE_AGENT) < target) {
            __builtin_amdgcn_s_sleep(2);
            if (++spins > 100000) {   // safety: if relaxed reads were stale, acquire instead of hanging
                while (__hip_atomic_load(cnt, __ATOMIC_ACQUIRE, __HIP_MEMORY_SCOPE_AGENT) < target)
                    __builtin_amdgcn_s_sleep(8);
                break;
            }
        }
    }
    __syncthreads();
}

// Hb layout: [parity][256 batch][256 hidden] u32 = (hi bf16) | (lo bf16 << 16).
__global__ __launch_bounds__(256) void lstm_persist(
    const float* __restrict__ x,
    const float* __restrict__ Wih1,
    const float* __restrict__ bias1,
    const float* __restrict__ bias2,
    const float* __restrict__ Whh1,
    const float* __restrict__ Wih2,
    const float* __restrict__ Whh2,
    u32* __restrict__ Hb1, u32* __restrict__ Hb2,
    u16* __restrict__ H2out, u32* bar)
{
    __shared__ __align__(16) u16 sh1hi[16 * 264], sh1lo[16 * 264];
    __shared__ __align__(16) u16 sh2hi[16 * 264], sh2lo[16 * 264];
    __shared__ float xs[TT * 16];
    __shared__ float gbuf1[4 * 16 * 18], gbuf2[4 * 16 * 18];
    __shared__ float wihs[64], b1s[64], b2s[64];

    const int tid = threadIdx.x;
    const int blk = blockIdx.x, gb = blk >> 4, hg = blk & 15;
    const int l = tid & 63, wv = tid >> 6;
    const int nloc = l & 15, kq = l >> 4;
    const int wrow = wv * 256 + hg * 16 + nloc;

    short8 bW1[8], bW2[8], bW3[8];
    load_bfrag(Whh1, wrow, kq, bW1);
    load_bfrag(Wih2, wrow, kq, bW2);
    load_bfrag(Whh2, wrow, kq, bW3);

    for (int idx = tid; idx < 16 * TT; idx += 256) {
        int b = idx >> 9, t = idx & 511;
        xs[t * 16 + b] = x[(gb * 16 + b) * TT + t];
    }
    if (tid < 64) {
        int rr = (tid >> 4) * 256 + hg * 16 + (tid & 15);
        wihs[tid] = Wih1[rr]; b1s[tid] = bias1[rr]; b2s[tid] = bias2[rr];
    }
    const int cb = tid >> 4, ci = tid & 15;
    const int bg = gb * 16 + cb, ig = hg * 16 + ci;
#pragma unroll
    for (int pp = 0; pp < 2; ++pp) {   // zero own patches, both parities (coherent stores)
        __hip_atomic_store(&Hb1[(pp * 256 + bg) * 256 + ig], 0u, __ATOMIC_RELAXED, __HIP_MEMORY_SCOPE_AGENT);
        __hip_atomic_store(&Hb2[(pp * 256 + bg) * 256 + ig], 0u, __ATOMIC_RELAXED, __HIP_MEMORY_SCOPE_AGENT);
    }
    float c1 = 0.f, c2 = 0.f;

    u32* cnt = bar + gb * 32;          // one 128B line per batch-group
    u32 p = 1;
    gbarrier(cnt, 16u * p); ++p;

    const int aoff = nloc * 264 + kq * 8;
    const int sb = tid >> 4, scol = (tid & 15) * 16;   // staging: row sb, 16 hidden from scol
    const int sbase = sb * 264 + scol;

    for (int k = 0; k <= TT; ++k, ++p) {
        const int rp = k & 1, wp = rp ^ 1;
        // stage h1(k-1), h2(k-2) via coherent 8B loads; unpack hi|lo into LDS
        {
            u64* p1 = (u64*)(Hb1 + ((rp * 256 + gb * 16 + sb) << 8) + scol);
            u64* p2 = (u64*)(Hb2 + ((rp * 256 + gb * 16 + sb) << 8) + scol);
            u64 v1[8], v2[8];
#pragma unroll
            for (int j = 0; j < 8; ++j)
                v1[j] = __hip_atomic_load(p1 + j, __ATOMIC_RELAXED, __HIP_MEMORY_SCOPE_AGENT);
#pragma unroll
            for (int j = 0; j < 8; ++j)
                v2[j] = __hip_atomic_load(p2 + j, __ATOMIC_RELAXED, __HIP_MEMORY_SCOPE_AGENT);
#pragma unroll
            for (int j = 0; j < 8; ++j) {
                u32 w0 = (u32)v1[j], w1 = (u32)(v1[j] >> 32);
                *(u32*)(sh1hi + sbase + 2 * j) = (w0 & 0xffffu) | (w1 << 16);
                *(u32*)(sh1lo + sbase + 2 * j) = (w0 >> 16) | (w1 & 0xffff0000u);
                w0 = (u32)v2[j]; w1 = (u32)(v2[j] >> 32);
                *(u32*)(sh2hi + sbase + 2 * j) = (w0 & 0xffffu) | (w1 << 16);
                *(u32*)(sh2lo + sbase + 2 * j) = (w0 >> 16) | (w1 & 0xffff0000u);
            }
        }
        __syncthreads();

        f32x4 acc1a = {0,0,0,0}, acc1b = {0,0,0,0};
        f32x4 acc2a = {0,0,0,0}, acc2b = {0,0,0,0};
        if (k < TT) {
#pragma unroll
            for (int kk = 0; kk < 8; ++kk) {
                short8 a = *(const short8*)(sh1hi + aoff + kk * 32);
                acc1a = __builtin_amdgcn_mfma_f32_16x16x32_bf16(a, bW1[kk], acc1a, 0, 0, 0);
                a = *(const short8*)(sh1lo + aoff + kk * 32);
                acc1b = __builtin_amdgcn_mfma_f32_16x16x32_bf16(a, bW1[kk], acc1b, 0, 0, 0);
            }
        }
        if (k > 0) {
#pragma unroll
            for (int kk = 0; kk < 8; ++kk) {
                short8 a = *(const short8*)(sh1hi + aoff + kk * 32);
                acc2a = __builtin_amdgcn_mfma_f32_16x16x32_bf16(a, bW2[kk], acc2a, 0, 0, 0);
                a = *(const short8*)(sh1lo + aoff + kk * 32);
                acc2b = __builtin_amdgcn_mfma_f32_16x16x32_bf16(a, bW2[kk], acc2b, 0, 0, 0);
                a = *(const short8*)(sh2hi + aoff + kk * 32);
                acc2a = __builtin_amdgcn_mfma_f32_16x16x32_bf16(a, bW3[kk], acc2a, 0, 0, 0);
                a = *(const short8*)(sh2lo + aoff + kk * 32);
                acc2b = __builtin_amdgcn_mfma_f32_16x16x32_bf16(a, bW3[kk], acc2b, 0, 0, 0);
            }
        }
#pragma unroll
        for (int r = 0; r < 4; ++r) {
            int m = (l >> 4) * 4 + r;
            gbuf1[(wv * 16 + m) * 18 + nloc] = acc1a[r] + acc1b[r];
            gbuf2[(wv * 16 + m) * 18 + nloc] = acc2a[r] + acc2b[r];
        }
        __syncthreads();

        if (k < TT) {   // cell 1, t = k
            float xv = xs[k * 16 + cb];
            float g0 = gbuf1[(0 * 16 + cb) * 18 + ci] + xv * wihs[ci]      + b1s[ci];
            float g1 = gbuf1[(1 * 16 + cb) * 18 + ci] + xv * wihs[16 + ci] + b1s[16 + ci];
            float g2 = gbuf1[(2 * 16 + cb) * 18 + ci] + xv * wihs[32 + ci] + b1s[32 + ci];
            float g3 = gbuf1[(3 * 16 + cb) * 18 + ci] + xv * wihs[48 + ci] + b1s[48 + ci];
            float ii = sigf(g0), ff = sigf(g1), gg = tanhf_(g2), oo = sigf(g3);
            c1 = ff * c1 + ii * gg;
            float h = oo * tanhf_(c1);
            u16 hi = f2bf(h); u32 word = (u32)hi | ((u32)f2bf(h - bf2f(hi)) << 16);
            __hip_atomic_store(&Hb1[(wp * 256 + bg) * 256 + ig], word,
                               __ATOMIC_RELAXED, __HIP_MEMORY_SCOPE_AGENT);
        }
        if (k > 0) {    // cell 2, t = k-1
            float g0 = gbuf2[(0 * 16 + cb) * 18 + ci] + b2s[ci];
            float g1 = gbuf2[(1 * 16 + cb) * 18 + ci] + b2s[16 + ci];
            float g2 = gbuf2[(2 * 16 + cb) * 18 + ci] + b2s[32 + ci];
            float g3 = gbuf2[(3 * 16 + cb) * 18 + ci] + b2s[48 + ci];
            float ii = sigf(g0), ff = sigf(g1), gg = tanhf_(g2), oo = sigf(g3);
            c2 = ff * c2 + ii * gg;
            float h = oo * tanhf_(c2);
            u16 hi = f2bf(h); u32 word = (u32)hi | ((u32)f2bf(h - bf2f(hi)) << 16);
            __hip_atomic_store(&Hb2[(wp * 256 + bg) * 256 + ig], word,
                               __ATOMIC_RELAXED, __HIP_MEMORY_SCOPE_AGENT);
            H2out[(bg * TT + (k - 1)) * 256 + ig] = hi;
        }
        gbarrier(cnt, 16u * p);
    }
}

// ---- fused attention: per 64-row tile, S1=tanh(H2@Wa1^T+ba1) -> S2=S1@Wa2^T+ba2
//      -> softmax rows -> out = sum_n p*h2*Wo + bo. MFMA for both matmuls.
__global__ __launch_bounds__(256) void attn_fused(
    const u16*  __restrict__ Wa1b, const u16* __restrict__ Wa2b,
    const float* __restrict__ ba1, const float* __restrict__ ba2,
    const float* __restrict__ Wo,  const float* __restrict__ bo,
    const u16*  __restrict__ H2,   float* __restrict__ out)
{
    __shared__ __align__(16) u16 sA[64 * 264];   // H2 tile
    __shared__ __align__(16) u16 sP[64 * 264];   // Y tile
    __shared__ float red[64 * 12];               // [m][w]: max / suml / sumw
    __shared__ float sb1[256], sb2[256], swo[256];

    const int tid = threadIdx.x;
    const int w = tid >> 6, l = tid & 63;
    const int c = l & 15, q = l >> 4;
    const int row0 = blockIdx.x * 64;

    // stage H2 tile: thread -> row r=tid>>2, 128B chunk qq=tid&3
    {
        const int r = tid >> 2, qq = tid & 3;
        const uint4* src = (const uint4*)(H2 + (row0 + r) * 256 + qq * 64);
#pragma unroll
        for (int j = 0; j < 8; ++j) {
            uint4 v = src[j];
            *(uint4*)(sA + r * 264 + qq * 64 + j * 8) = v;
        }
    }
    if (tid < 256) { sb1[tid] = ba1[tid]; sb2[tid] = ba2[tid]; swo[tid] = Wo[tid]; }
    __syncthreads();

    f32x4 acc[4][4];   // [mi][ni]
#pragma unroll
    for (int mi = 0; mi < 4; ++mi)
#pragma unroll
        for (int ni = 0; ni < 4; ++ni) acc[mi][ni] = (f32x4){0,0,0,0};

    // ---- matmul 1: S1 = H2tile @ Wa1^T
#pragma unroll
    for (int ni = 0; ni < 4; ++ni) {
        const int row = w * 64 + ni * 16 + c;
        const u16* wp = Wa1b + row * 256 + q * 8;
        short8 bW[8];
#pragma unroll
        for (int kk = 0; kk < 8; ++kk) bW[kk] = *(const short8*)(wp + kk * 32);
#pragma unroll
        for (int kk = 0; kk < 8; ++kk)
#pragma unroll
            for (int mi = 0; mi < 4; ++mi) {
                short8 a = *(const short8*)(sA + (mi * 16 + c) * 264 + q * 8 + kk * 32);
                acc[mi][ni] = __builtin_amdgcn_mfma_f32_16x16x32_bf16(a, bW[kk], acc[mi][ni], 0, 0, 0);
            }
    }
    // epilogue 1: Y = tanh(S1 + ba1) -> sP (bf16, A-layout for matmul 2)
#pragma unroll
    for (int mi = 0; mi < 4; ++mi)
#pragma unroll
        for (int ni = 0; ni < 4; ++ni) {
            const int n = w * 64 + ni * 16 + c;
            const float bj = sb1[n];
#pragma unroll
            for (int r = 0; r < 4; ++r) {
                int m = mi * 16 + q * 4 + r;
                sP[m * 264 + n] = f2bf(tanhf(acc[mi][ni][r] + bj));
            }
        }
    __syncthreads();

    // ---- matmul 2: S2 = Y @ Wa2^T
#pragma unroll
    for (int mi = 0; mi < 4; ++mi)
#pragma unroll
        for (int ni = 0; ni < 4; ++ni) acc[mi][ni] = (f32x4){0,0,0,0};
#pragma unroll
    for (int ni = 0; ni < 4; ++ni) {
        const int row = w * 64 + ni * 16 + c;
        const u16* wp = Wa2b + row * 256 + q * 8;
        short8 bW[8];
#pragma unroll
        for (int kk = 0; kk < 8; ++kk) bW[kk] = *(const short8*)(wp + kk * 32);
#pragma unroll
        for (int kk = 0; kk < 8; ++kk)
#pragma unroll
            for (int mi = 0; mi < 4; ++mi) {
                short8 a = *(const short8*)(sP + (mi * 16 + c) * 264 + q * 8 + kk * 32);
                acc[mi][ni] = __builtin_amdgcn_mfma_f32_16x16x32_bf16(a, bW[kk], acc[mi][ni], 0, 0, 0);
            }
    }

    // scores = S2 + ba2 ; row max over n (in-lane over ni, xor-shuffle over c, LDS over waves)
    float mx[4][4];   // [mi][r]
#pragma unroll
    for (int mi = 0; mi < 4; ++mi)
#pragma unroll
        for (int r = 0; r < 4; ++r) mx[mi][r] = -1e30f;
#pragma unroll
    for (int mi = 0; mi < 4; ++mi)
#pragma unroll
        for (int ni = 0; ni < 4; ++ni) {
            const float bj = sb2[w * 64 + ni * 16 + c];
#pragma unroll
            for (int r = 0; r < 4; ++r) {
                float s = acc[mi][ni][r] + bj;
                acc[mi][ni][r] = s;
                mx[mi][r] = fmaxf(mx[mi][r], s);
            }
        }
#pragma unroll
    for (int off = 1; off < 16; off <<= 1)
#pragma unroll
        for (int mi = 0; mi < 4; ++mi)
#pragma unroll
            for (int r = 0; r < 4; ++r) mx[mi][r] = fmaxf(mx[mi][r], __shfl_xor(mx[mi][r], off));
    if (c == 0)
#pragma unroll
        for (int mi = 0; mi < 4; ++mi)
#pragma unroll
            for (int r = 0; r < 4; ++r) red[(mi * 16 + q * 4 + r) * 12 + w] = mx[mi][r];
    __syncthreads();
#pragma unroll
    for (int mi = 0; mi < 4; ++mi)
#pragma unroll
        for (int r = 0; r < 4; ++r) {
            const float* rp = red + (mi * 16 + q * 4 + r) * 12;
            mx[mi][r] = fmaxf(fmaxf(rp[0], rp[1]), fmaxf(rp[2], rp[3]));
        }
    // exp + sums
    float suml[4][4], sumw[4][4];
#pragma unroll
    for (int mi = 0; mi < 4; ++mi)
#pragma unroll
        for (int r = 0; r < 4; ++r) { suml[mi][r] = 0.f; sumw[mi][r] = 0.f; }
#pragma unroll
    for (int mi = 0; mi < 4; ++mi)
#pragma unroll
        for (int ni = 0; ni < 4; ++ni) {
            const int n = w * 64 + ni * 16 + c;
            const float wov = swo[n];
#pragma unroll
            for (int r = 0; r < 4; ++r) {
                int m = mi * 16 + q * 4 + r;
                float e = __expf(acc[mi][ni][r] - mx[mi][r]);
                suml[mi][r] += e;
                sumw[mi][r] += e * bf2f(sA[m * 264 + n]) * wov;
            }
        }
#pragma unroll
    for (int off = 1; off < 16; off <<= 1)
#pragma unroll
        for (int mi = 0; mi < 4; ++mi)
#pragma unroll
            for (int r = 0; r < 4; ++r) {
                suml[mi][r] += __shfl_xor(suml[mi][r], off);
                sumw[mi][r] += __shfl_xor(sumw[mi][r], off);
            }
    __syncthreads();
    if (c == 0)
#pragma unroll
        for (int mi = 0; mi < 4; ++mi)
#pragma unroll
            for (int r = 0; r < 4; ++r) {
                int m = mi * 16 + q * 4 + r;
                red[m * 12 + 4 + w] = suml[mi][r];
                red[m * 12 + 8 + w] = sumw[mi][r];
            }
    __syncthreads();
    if (tid < 64) {
        const float* rp = red + tid * 12;
        float lsum = rp[4] + rp[5] + rp[6] + rp[7];
        float wsum = rp[8] + rp[9] + rp[10] + rp[11];
        out[row0 + tid] = wsum / lsum + bo[0];
    }
}

extern "C" void kernel_launch(void* const* d_in, const int* in_sizes, int n_in,
                              void* d_out, int out_size, void* d_ws, size_t ws_size,
                              hipStream_t stream) {
    const float* x    = (const float*)d_in[0];
    const float* Wih1 = (const float*)d_in[1];
    const float* bih1 = (const float*)d_in[2];
    const float* Whh1 = (const float*)d_in[3];
    const float* bhh1 = (const float*)d_in[4];
    const float* Wih2 = (const float*)d_in[5];
    const float* bih2 = (const float*)d_in[6];
    const float* Whh2 = (const float*)d_in[7];
    const float* bhh2 = (const float*)d_in[8];
    const float* Wa1  = (const float*)d_in[9];
    const float* ba1  = (const float*)d_in[10];
    const float* Wa2  = (const float*)d_in[11];
    const float* ba2  = (const float*)d_in[12];
    const float* Wo   = (const float*)d_in[13];
    const float* bo   = (const float*)d_in[14];

    char* ws = (char*)d_ws;
    u16*   Wa1b  = (u16*)(ws + 0);                  // 128 KB
    u16*   Wa2b  = (u16*)(ws + 131072);             // 128 KB
    float* bias1 = (float*)(ws + 262144);           // 4 KB
    float* bias2 = (float*)(ws + 266240);           // 4 KB
    u32*   bar   = (u32*)(ws + 270336);             // 2 KB (16 x 128B lines)
    u32*   Hb1   = (u32*)(ws + 524288);             // 512 KB [2][256][256] u32
    u32*   Hb2   = (u32*)(ws + 1048576);            // 512 KB
    u16*   H2    = (u16*)(ws + 2097152);            // 64 MB
    float* out   = (float*)d_out;

    hipMemsetAsync(bar, 0, 4096, stream);
    bias_kernel<<<4, 256, 0, stream>>>(bih1, bhh1, bih2, bhh2, bias1, bias2);
    cvt_bf_kernel<<<256, 256, 0, stream>>>(Wa1, Wa1b, 65536);
    cvt_bf_kernel<<<256, 256, 0, stream>>>(Wa2, Wa2b, 65536);

    lstm_persist<<<256, 256, 0, stream>>>(x, Wih1, bias1, bias2,
                                          Whh1, Wih2, Whh2, Hb1, Hb2, H2, bar);
    attn_fused<<<2048, 256, 0, stream>>>(Wa1b, Wa2b, ba1, ba2, Wo, bo, H2, out);
}

// Round 6
// 2630.625 us; speedup vs baseline: 5.8478x; 1.0291x over previous
//
// pendulumRNNSA — persistent 2-layer LSTM (B=256,T=512,H=256) + fused MFMA attention.
//
// Round 6 — consolidation after the round-5 timeout:
//  * Coherence reverted to the ROUND-3-PROVEN path: ALL inter-block traffic
//    (h exchange + flags) via __hip_atomic RELAXED @ AGENT scope (sc0+sc1,
//    coherent at L3). No fences, no placement assumptions, no inline asm.
//    (Round 5's co-XCD fast path made the spin bound a de-facto hang when
//    XCC detection mis-fired — dropped until it can be probe-verified.)
//  * Flag barrier kept: each block posts its phase to a PRIVATE 128B slot
//    (parallel stores, no RMW serialization — round 3's fetch_add chain was
//    ~2-3us/phase); waiters poll the group's 16 slots with 16 lanes.
//  * LDS: fragment reads shared between gates1*W1 and gates2*W2 MFMAs;
//    staging via b128 writes.
//  * H2out (HBM, attention input) stored AFTER the flag post — off the
//    inter-block critical path.
//  * h exchanged as (hi|lo) bf16 pair in one u32 (~fp23 recurrence precision).
#include <hip/hip_runtime.h>
#include <hip/hip_bf16.h>

#define HD   256
#define TT   512

typedef unsigned short u16;
typedef unsigned int   u32;
typedef unsigned long long u64;
typedef __attribute__((ext_vector_type(8))) short  short8;
typedef __attribute__((ext_vector_type(4))) float  f32x4;

__device__ __forceinline__ float bf2f(u16 v) { return __uint_as_float(((u32)v) << 16); }
__device__ __forceinline__ u16 f2bf(float f) {
    u32 u = __float_as_uint(f);
    u32 r = u + 0x7fffu + ((u >> 16) & 1u);   // RNE
    return (u16)(r >> 16);
}
__device__ __forceinline__ float sigf(float x)  { return __builtin_amdgcn_rcpf(1.f + __expf(-x)); }
__device__ __forceinline__ float tanhf_(float x){ float e = __expf(-2.f * x);
                                                  return 2.f * __builtin_amdgcn_rcpf(1.f + e) - 1.f; }

__global__ void cvt_bf_kernel(const float* __restrict__ src, u16* __restrict__ dst, int n) {
    int idx = blockIdx.x * 256 + threadIdx.x;
    if (idx < n) dst[idx] = f2bf(src[idx]);
}

__global__ void bias_kernel(const float* __restrict__ a1, const float* __restrict__ b1,
                            const float* __restrict__ a2, const float* __restrict__ b2,
                            float* __restrict__ o1, float* __restrict__ o2) {
    int i = blockIdx.x * 256 + threadIdx.x;
    o1[i] = a1[i] + b1[i];
    o2[i] = a2[i] + b2[i];
}

__device__ __forceinline__ void load_bfrag(const float* __restrict__ W, int row, int kq, short8* bw) {
#pragma unroll
    for (int kk = 0; kk < 8; ++kk) {
        const float* p = W + row * 256 + kk * 32 + kq * 8;
        short8 s;
#pragma unroll
        for (int j = 0; j < 8; ++j) s[j] = (short)f2bf(p[j]);
        bw[kk] = s;
    }
}

// flag wait: lanes 0..15 poll the group's 16 slots (relaxed agent loads) until
// >= target. Bounded spin so a logic error degrades to wrong-answer, not hang.
__device__ __forceinline__ void flag_wait(const u32* flags, int gb, u32 target) {
    if (threadIdx.x < 16) {
        const u32* slot = flags + (gb * 16 + (int)threadIdx.x) * 32;
        int sp = 0;
        while (__hip_atomic_load(slot, __ATOMIC_RELAXED, __HIP_MEMORY_SCOPE_AGENT) < target) {
            if (++sp > (1 << 24)) break;
        }
    }
    __syncthreads();
}

// flag post: __syncthreads drains vmcnt(0) (all h stores at the coherent point),
// then the leader publishes the phase to this block's private slot. Parallel
// across blocks — no RMW chain.
__device__ __forceinline__ void flag_post(u32* flags, int slotidx, u32 val) {
    __syncthreads();
    if (threadIdx.x == 0)
        __hip_atomic_store(flags + slotidx * 32, val, __ATOMIC_RELAXED, __HIP_MEMORY_SCOPE_AGENT);
}

// Hb layout: [parity][256 batch][256 hidden] u32 = (hi bf16) | (lo bf16 << 16).
__global__ __launch_bounds__(256) void lstm_persist(
    const float* __restrict__ x,
    const float* __restrict__ Wih1,
    const float* __restrict__ bias1,
    const float* __restrict__ bias2,
    const float* __restrict__ Whh1,
    const float* __restrict__ Wih2,
    const float* __restrict__ Whh2,
    u32* __restrict__ Hb1, u32* __restrict__ Hb2,
    u16* __restrict__ H2out, u32* flags)
{
    __shared__ __align__(16) u16 sh1hi[16 * 264], sh1lo[16 * 264];
    __shared__ __align__(16) u16 sh2hi[16 * 264], sh2lo[16 * 264];
    __shared__ float xs[TT * 16];
    __shared__ float gbuf1[4 * 16 * 18], gbuf2[4 * 16 * 18];
    __shared__ float wihs[64], b1s[64], b2s[64];

    const int tid = threadIdx.x;
    const int blk = blockIdx.x, gb = blk >> 4, hg = blk & 15;
    const int l = tid & 63, wv = tid >> 6;
    const int nloc = l & 15, kq = l >> 4;
    const int wrow = wv * 256 + hg * 16 + nloc;

    short8 bW1[8], bW2[8], bW3[8];
    load_bfrag(Whh1, wrow, kq, bW1);
    load_bfrag(Wih2, wrow, kq, bW2);
    load_bfrag(Whh2, wrow, kq, bW3);

    for (int idx = tid; idx < 16 * TT; idx += 256) {
        int b = idx >> 9, t = idx & 511;
        xs[t * 16 + b] = x[(gb * 16 + b) * TT + t];
    }
    if (tid < 64) {
        int rr = (tid >> 4) * 256 + hg * 16 + (tid & 15);
        wihs[tid] = Wih1[rr]; b1s[tid] = bias1[rr]; b2s[tid] = bias2[rr];
    }

    // zero own state patches (both parities) — ws is re-poisoned each launch
    const int cb = tid >> 4, ci = tid & 15;
    const int bg = gb * 16 + cb, ig = hg * 16 + ci;
#pragma unroll
    for (int pp = 0; pp < 2; ++pp) {
        __hip_atomic_store(&Hb1[((pp * 256 + bg) << 8) + ig], 0u, __ATOMIC_RELAXED, __HIP_MEMORY_SCOPE_AGENT);
        __hip_atomic_store(&Hb2[((pp * 256 + bg) << 8) + ig], 0u, __ATOMIC_RELAXED, __HIP_MEMORY_SCOPE_AGENT);
    }
    float c1 = 0.f, c2 = 0.f;

    flag_post(flags, gb * 16 + hg, 1u);   // phase-1: zeroing done

    const int aoff = nloc * 264 + kq * 8;
    const int sb = tid >> 4, scol = (tid & 15) * 16;   // staging: row sb, cols scol..scol+15
    const int sbase = sb * 264 + scol;

    for (int k = 0; k <= TT; ++k) {
        flag_wait(flags, gb, (u32)(k + 1));

        const int rp = k & 1, wp = rp ^ 1;
        // ---- stage h1(k-1), h2(k-2): 16 u32 from each buffer per thread (8B loads)
        {
            const u32* p1 = Hb1 + ((rp * 256 + gb * 16 + sb) << 8) + scol;
            const u32* p2 = Hb2 + ((rp * 256 + gb * 16 + sb) << 8) + scol;
            u32 w1v[16], w2v[16];
#pragma unroll
            for (int j = 0; j < 8; ++j) {
                u64 t = __hip_atomic_load((const u64*)p1 + j, __ATOMIC_RELAXED, __HIP_MEMORY_SCOPE_AGENT);
                w1v[2 * j] = (u32)t; w1v[2 * j + 1] = (u32)(t >> 32);
            }
#pragma unroll
            for (int j = 0; j < 8; ++j) {
                u64 t = __hip_atomic_load((const u64*)p2 + j, __ATOMIC_RELAXED, __HIP_MEMORY_SCOPE_AGENT);
                w2v[2 * j] = (u32)t; w2v[2 * j + 1] = (u32)(t >> 32);
            }
            // unpack hi|lo, vectorized LDS stores (2x b128 per plane per thread)
            u32 h1h[8], h1l[8], h2h[8], h2l[8];
#pragma unroll
            for (int i = 0; i < 8; ++i) {
                u32 a = w1v[2 * i], b = w1v[2 * i + 1];
                h1h[i] = (a & 0xffffu) | (b << 16);
                h1l[i] = (a >> 16) | (b & 0xffff0000u);
                a = w2v[2 * i]; b = w2v[2 * i + 1];
                h2h[i] = (a & 0xffffu) | (b << 16);
                h2l[i] = (a >> 16) | (b & 0xffff0000u);
            }
            *(uint4*)(sh1hi + sbase) = *(uint4*)(h1h);     *(uint4*)(sh1hi + sbase + 8) = *(uint4*)(h1h + 4);
            *(uint4*)(sh1lo + sbase) = *(uint4*)(h1l);     *(uint4*)(sh1lo + sbase + 8) = *(uint4*)(h1l + 4);
            *(uint4*)(sh2hi + sbase) = *(uint4*)(h2h);     *(uint4*)(sh2hi + sbase + 8) = *(uint4*)(h2h + 4);
            *(uint4*)(sh2lo + sbase) = *(uint4*)(h2l);     *(uint4*)(sh2lo + sbase + 8) = *(uint4*)(h2l + 4);
        }
        __syncthreads();

        f32x4 acc1a = {0,0,0,0}, acc1b = {0,0,0,0};
        f32x4 acc2a = {0,0,0,0}, acc2b = {0,0,0,0};
#pragma unroll
        for (int kk = 0; kk < 8; ++kk) {
            short8 a1h = *(const short8*)(sh1hi + aoff + kk * 32);
            short8 a1l = *(const short8*)(sh1lo + aoff + kk * 32);
            if (k < TT) {
                acc1a = __builtin_amdgcn_mfma_f32_16x16x32_bf16(a1h, bW1[kk], acc1a, 0, 0, 0);
                acc1b = __builtin_amdgcn_mfma_f32_16x16x32_bf16(a1l, bW1[kk], acc1b, 0, 0, 0);
            }
            if (k > 0) {
                acc2a = __builtin_amdgcn_mfma_f32_16x16x32_bf16(a1h, bW2[kk], acc2a, 0, 0, 0);
                acc2b = __builtin_amdgcn_mfma_f32_16x16x32_bf16(a1l, bW2[kk], acc2b, 0, 0, 0);
                short8 a2h = *(const short8*)(sh2hi + aoff + kk * 32);
                short8 a2l = *(const short8*)(sh2lo + aoff + kk * 32);
                acc2a = __builtin_amdgcn_mfma_f32_16x16x32_bf16(a2h, bW3[kk], acc2a, 0, 0, 0);
                acc2b = __builtin_amdgcn_mfma_f32_16x16x32_bf16(a2l, bW3[kk], acc2b, 0, 0, 0);
            }
        }
        // D layout: col(n)=lane&15, row(m)=(lane>>4)*4+reg
#pragma unroll
        for (int r = 0; r < 4; ++r) {
            int m = (l >> 4) * 4 + r;
            gbuf1[(wv * 16 + m) * 18 + nloc] = acc1a[r] + acc1b[r];
            gbuf2[(wv * 16 + m) * 18 + nloc] = acc2a[r] + acc2b[r];
        }
        __syncthreads();

        u16 hi2 = 0;
        if (k < TT) {   // cell 1, t = k
            float xv = xs[k * 16 + cb];
            float g0 = gbuf1[(0 * 16 + cb) * 18 + ci] + xv * wihs[ci]      + b1s[ci];
            float g1 = gbuf1[(1 * 16 + cb) * 18 + ci] + xv * wihs[16 + ci] + b1s[16 + ci];
            float g2 = gbuf1[(2 * 16 + cb) * 18 + ci] + xv * wihs[32 + ci] + b1s[32 + ci];
            float g3 = gbuf1[(3 * 16 + cb) * 18 + ci] + xv * wihs[48 + ci] + b1s[48 + ci];
            float ii = sigf(g0), ff = sigf(g1), gg = tanhf_(g2), oo = sigf(g3);
            c1 = ff * c1 + ii * gg;
            float h = oo * tanhf_(c1);
            u16 hi = f2bf(h); u32 word = (u32)hi | ((u32)f2bf(h - bf2f(hi)) << 16);
            __hip_atomic_store(&Hb1[((wp * 256 + bg) << 8) + ig], word,
                               __ATOMIC_RELAXED, __HIP_MEMORY_SCOPE_AGENT);
        }
        if (k > 0) {    // cell 2, t = k-1
            float g0 = gbuf2[(0 * 16 + cb) * 18 + ci] + b2s[ci];
            float g1 = gbuf2[(1 * 16 + cb) * 18 + ci] + b2s[16 + ci];
            float g2 = gbuf2[(2 * 16 + cb) * 18 + ci] + b2s[32 + ci];
            float g3 = gbuf2[(3 * 16 + cb) * 18 + ci] + b2s[48 + ci];
            float ii = sigf(g0), ff = sigf(g1), gg = tanhf_(g2), oo = sigf(g3);
            c2 = ff * c2 + ii * gg;
            float h = oo * tanhf_(c2);
            hi2 = f2bf(h); u32 word = (u32)hi2 | ((u32)f2bf(h - bf2f(hi2)) << 16);
            __hip_atomic_store(&Hb2[((wp * 256 + bg) << 8) + ig], word,
                               __ATOMIC_RELAXED, __HIP_MEMORY_SCOPE_AGENT);
        }
        flag_post(flags, gb * 16 + hg, (u32)(k + 2));
        // HBM store for the attention pass — AFTER the post, off the critical path
        if (k > 0) H2out[(bg * TT + (k - 1)) * 256 + ig] = hi2;
    }
}

// ---- fused attention: per 64-row tile, S1=tanh(H2@Wa1^T+ba1) -> S2=S1@Wa2^T+ba2
//      -> softmax rows -> out = sum_n p*h2*Wo + bo. MFMA for both matmuls.
__global__ __launch_bounds__(256) void attn_fused(
    const u16*  __restrict__ Wa1b, const u16* __restrict__ Wa2b,
    const float* __restrict__ ba1, const float* __restrict__ ba2,
    const float* __restrict__ Wo,  const float* __restrict__ bo,
    const u16*  __restrict__ H2,   float* __restrict__ out)
{
    __shared__ __align__(16) u16 sA[64 * 264];
    __shared__ __align__(16) u16 sP[64 * 264];
    __shared__ float red[64 * 12];
    __shared__ float sb1[256], sb2[256], swo[256];

    const int tid = threadIdx.x;
    const int w = tid >> 6, l = tid & 63;
    const int c = l & 15, q = l >> 4;
    const int row0 = blockIdx.x * 64;

    {
        const int r = tid >> 2, qq = tid & 3;
        const uint4* src = (const uint4*)(H2 + (row0 + r) * 256 + qq * 64);
#pragma unroll
        for (int j = 0; j < 8; ++j) {
            uint4 v = src[j];
            *(uint4*)(sA + r * 264 + qq * 64 + j * 8) = v;
        }
    }
    if (tid < 256) { sb1[tid] = ba1[tid]; sb2[tid] = ba2[tid]; swo[tid] = Wo[tid]; }
    __syncthreads();

    f32x4 acc[4][4];
#pragma unroll
    for (int mi = 0; mi < 4; ++mi)
#pragma unroll
        for (int ni = 0; ni < 4; ++ni) acc[mi][ni] = (f32x4){0,0,0,0};

#pragma unroll
    for (int ni = 0; ni < 4; ++ni) {
        const int row = w * 64 + ni * 16 + c;
        const u16* wp = Wa1b + row * 256 + q * 8;
        short8 bW[8];
#pragma unroll
        for (int kk = 0; kk < 8; ++kk) bW[kk] = *(const short8*)(wp + kk * 32);
#pragma unroll
        for (int kk = 0; kk < 8; ++kk)
#pragma unroll
            for (int mi = 0; mi < 4; ++mi) {
                short8 a = *(const short8*)(sA + (mi * 16 + c) * 264 + q * 8 + kk * 32);
                acc[mi][ni] = __builtin_amdgcn_mfma_f32_16x16x32_bf16(a, bW[kk], acc[mi][ni], 0, 0, 0);
            }
    }
#pragma unroll
    for (int mi = 0; mi < 4; ++mi)
#pragma unroll
        for (int ni = 0; ni < 4; ++ni) {
            const int n = w * 64 + ni * 16 + c;
            const float bj = sb1[n];
#pragma unroll
            for (int r = 0; r < 4; ++r) {
                int m = mi * 16 + q * 4 + r;
                sP[m * 264 + n] = f2bf(tanhf(acc[mi][ni][r] + bj));
            }
        }
    __syncthreads();

#pragma unroll
    for (int mi = 0; mi < 4; ++mi)
#pragma unroll
        for (int ni = 0; ni < 4; ++ni) acc[mi][ni] = (f32x4){0,0,0,0};
#pragma unroll
    for (int ni = 0; ni < 4; ++ni) {
        const int row = w * 64 + ni * 16 + c;
        const u16* wp = Wa2b + row * 256 + q * 8;
        short8 bW[8];
#pragma unroll
        for (int kk = 0; kk < 8; ++kk) bW[kk] = *(const short8*)(wp + kk * 32);
#pragma unroll
        for (int kk = 0; kk < 8; ++kk)
#pragma unroll
            for (int mi = 0; mi < 4; ++mi) {
                short8 a = *(const short8*)(sP + (mi * 16 + c) * 264 + q * 8 + kk * 32);
                acc[mi][ni] = __builtin_amdgcn_mfma_f32_16x16x32_bf16(a, bW[kk], acc[mi][ni], 0, 0, 0);
            }
    }

    float mx[4][4];
#pragma unroll
    for (int mi = 0; mi < 4; ++mi)
#pragma unroll
        for (int r = 0; r < 4; ++r) mx[mi][r] = -1e30f;
#pragma unroll
    for (int mi = 0; mi < 4; ++mi)
#pragma unroll
        for (int ni = 0; ni < 4; ++ni) {
            const float bj = sb2[w * 64 + ni * 16 + c];
#pragma unroll
            for (int r = 0; r < 4; ++r) {
                float s = acc[mi][ni][r] + bj;
                acc[mi][ni][r] = s;
                mx[mi][r] = fmaxf(mx[mi][r], s);
            }
        }
#pragma unroll
    for (int off = 1; off < 16; off <<= 1)
#pragma unroll
        for (int mi = 0; mi < 4; ++mi)
#pragma unroll
            for (int r = 0; r < 4; ++r) mx[mi][r] = fmaxf(mx[mi][r], __shfl_xor(mx[mi][r], off));
    if (c == 0)
#pragma unroll
        for (int mi = 0; mi < 4; ++mi)
#pragma unroll
            for (int r = 0; r < 4; ++r) red[(mi * 16 + q * 4 + r) * 12 + w] = mx[mi][r];
    __syncthreads();
#pragma unroll
    for (int mi = 0; mi < 4; ++mi)
#pragma unroll
        for (int r = 0; r < 4; ++r) {
            const float* rp = red + (mi * 16 + q * 4 + r) * 12;
            mx[mi][r] = fmaxf(fmaxf(rp[0], rp[1]), fmaxf(rp[2], rp[3]));
        }
    float suml[4][4], sumw[4][4];
#pragma unroll
    for (int mi = 0; mi < 4; ++mi)
#pragma unroll
        for (int r = 0; r < 4; ++r) { suml[mi][r] = 0.f; sumw[mi][r] = 0.f; }
#pragma unroll
    for (int mi = 0; mi < 4; ++mi)
#pragma unroll
        for (int ni = 0; ni < 4; ++ni) {
            const int n = w * 64 + ni * 16 + c;
            const float wov = swo[n];
#pragma unroll
            for (int r = 0; r < 4; ++r) {
                int m = mi * 16 + q * 4 + r;
                float e = __expf(acc[mi][ni][r] - mx[mi][r]);
                suml[mi][r] += e;
                sumw[mi][r] += e * bf2f(sA[m * 264 + n]) * wov;
            }
        }
#pragma unroll
    for (int off = 1; off < 16; off <<= 1)
#pragma unroll
        for (int mi = 0; mi < 4; ++mi)
#pragma unroll
            for (int r = 0; r < 4; ++r) {
                suml[mi][r] += __shfl_xor(suml[mi][r], off);
                sumw[mi][r] += __shfl_xor(sumw[mi][r], off);
            }
    __syncthreads();
    if (c == 0)
#pragma unroll
        for (int mi = 0; mi < 4; ++mi)
#pragma unroll
            for (int r = 0; r < 4; ++r) {
                int m = mi * 16 + q * 4 + r;
                red[m * 12 + 4 + w] = suml[mi][r];
                red[m * 12 + 8 + w] = sumw[mi][r];
            }
    __syncthreads();
    if (tid < 64) {
        const float* rp = red + tid * 12;
        float lsum = rp[4] + rp[5] + rp[6] + rp[7];
        float wsum = rp[8] + rp[9] + rp[10] + rp[11];
        out[row0 + tid] = wsum / lsum + bo[0];
    }
}

extern "C" void kernel_launch(void* const* d_in, const int* in_sizes, int n_in,
                              void* d_out, int out_size, void* d_ws, size_t ws_size,
                              hipStream_t stream) {
    const float* x    = (const float*)d_in[0];
    const float* Wih1 = (const float*)d_in[1];
    const float* bih1 = (const float*)d_in[2];
    const float* Whh1 = (const float*)d_in[3];
    const float* bhh1 = (const float*)d_in[4];
    const float* Wih2 = (const float*)d_in[5];
    const float* bih2 = (const float*)d_in[6];
    const float* Whh2 = (const float*)d_in[7];
    const float* bhh2 = (const float*)d_in[8];
    const float* Wa1  = (const float*)d_in[9];
    const float* ba1  = (const float*)d_in[10];
    const float* Wa2  = (const float*)d_in[11];
    const float* ba2  = (const float*)d_in[12];
    const float* Wo   = (const float*)d_in[13];
    const float* bo   = (const float*)d_in[14];

    char* ws = (char*)d_ws;
    u16*   Wa1b  = (u16*)(ws + 0);                  // 128 KB
    u16*   Wa2b  = (u16*)(ws + 131072);             // 128 KB
    float* bias1 = (float*)(ws + 262144);           // 4 KB
    float* bias2 = (float*)(ws + 266240);           // 4 KB
    u32*   flags = (u32*)(ws + 270336);             // 32 KB (256 x 128B slots)
    u32*   Hb1   = (u32*)(ws + 524288);             // 512 KB [2][256][256] u32
    u32*   Hb2   = (u32*)(ws + 1048576);            // 512 KB
    u16*   H2    = (u16*)(ws + 2097152);            // 64 MB
    float* out   = (float*)d_out;

    (void)hipMemsetAsync(flags, 0, 32768, stream);
    bias_kernel<<<4, 256, 0, stream>>>(bih1, bhh1, bih2, bhh2, bias1, bias2);
    cvt_bf_kernel<<<256, 256, 0, stream>>>(Wa1, Wa1b, 65536);
    cvt_bf_kernel<<<256, 256, 0, stream>>>(Wa2, Wa2b, 65536);

    lstm_persist<<<256, 256, 0, stream>>>(x, Wih1, bias1, bias2,
                                          Whh1, Wih2, Whh2, Hb1, Hb2, H2, flags);
    attn_fused<<<2048, 256, 0, stream>>>(Wa1b, Wa2b, ba1, ba2, Wo, bo, H2, out);
}